// Round 2
// baseline (2884.016 us; speedup 1.0000x reference)
//
#include <hip/hip_runtime.h>
#include <cmath>

// Memory_76957224010242: 100-step Adam inference loop.
// Reformulated: G = W^T W (2048^2), u = (x-c)@W once; per-iter s = r@G fused
// with Adam update + loss reduction in the GEMM epilogue.
// WS layout (needs ~50.5 MB): Wt | Gbf | xcbf | u | r | m | v | rbf0 | rbf1 | xc2 | lossPart

#define B_SZ 512
#define H_SZ 2048
#define D_SZ 4096
#define ITERS 100

typedef __attribute__((ext_vector_type(8))) short short8;
typedef __attribute__((ext_vector_type(4))) float f32x4;

__device__ __forceinline__ unsigned short f2bf(float f) {
    unsigned u = __float_as_uint(f);
    u = (u + 0x7fffu + ((u >> 16) & 1u)) >> 16;  // RNE
    return (unsigned short)u;
}

// ---- W (D,H) f32 -> Wt (H,D) bf16 (transpose + cast) ----
__global__ __launch_bounds__(256) void k_transpose(const float* __restrict__ W,
                                                   unsigned short* __restrict__ Wt) {
    __shared__ unsigned short tile[64][72];  // +8 pad
    const int d0 = blockIdx.x * 64, h0 = blockIdx.y * 64;
    const int t = threadIdx.x;
    const int lr = t >> 6, lc = t & 63;
#pragma unroll
    for (int rr = 0; rr < 16; ++rr) {
        const int dl = rr * 4 + lr;
        tile[dl][lc] = f2bf(W[(size_t)(d0 + dl) * H_SZ + h0 + lc]);
    }
    __syncthreads();
#pragma unroll
    for (int rr = 0; rr < 16; ++rr) {
        const int hl = rr * 4 + lr;
        Wt[(size_t)(h0 + hl) * D_SZ + d0 + lc] = tile[lc][hl];
    }
}

// ---- xc = (x - c) as bf16, xc2[b] = sum_d (x-c)^2 (exact fp32) ----
__global__ __launch_bounds__(256) void k_prepx(const float* __restrict__ x, const float* __restrict__ c,
                                               unsigned short* __restrict__ xcbf, float* __restrict__ xc2) {
    const int b = blockIdx.x, t = threadIdx.x;
    const float* xr = x + (size_t)b * D_SZ;
    unsigned short* orow = xcbf + (size_t)b * D_SZ;
    float acc = 0.f;
#pragma unroll
    for (int ch = 0; ch < 2; ++ch) {
        const int base = (ch * 256 + t) * 8;
        const float4 v0 = *(const float4*)(xr + base);
        const float4 v1 = *(const float4*)(xr + base + 4);
        const float4 c0 = *(const float4*)(c + base);
        const float4 c1 = *(const float4*)(c + base + 4);
        const float e0 = v0.x - c0.x, e1 = v0.y - c0.y, e2 = v0.z - c0.z, e3 = v0.w - c0.w;
        const float e4 = v1.x - c1.x, e5 = v1.y - c1.y, e6 = v1.z - c1.z, e7 = v1.w - c1.w;
        acc += e0 * e0 + e1 * e1 + e2 * e2 + e3 * e3 + e4 * e4 + e5 * e5 + e6 * e6 + e7 * e7;
        short8 ov;
        ov[0] = (short)f2bf(e0); ov[1] = (short)f2bf(e1); ov[2] = (short)f2bf(e2); ov[3] = (short)f2bf(e3);
        ov[4] = (short)f2bf(e4); ov[5] = (short)f2bf(e5); ov[6] = (short)f2bf(e6); ov[7] = (short)f2bf(e7);
        *(short8*)(orow + base) = ov;
    }
#pragma unroll
    for (int off = 32; off > 0; off >>= 1) acc += __shfl_down(acc, off);
    __shared__ float wred[4];
    if ((t & 63) == 0) wred[t >> 6] = acc;
    __syncthreads();
    if (t == 0) xc2[b] = wred[0] + wred[1] + wred[2] + wred[3];
}

// ---- r = r0; m = v = 0; rbf0 = bf16(r0) ----
__global__ __launch_bounds__(256) void k_init(const float* __restrict__ r0, float* __restrict__ r,
                                              float* __restrict__ m, float* __restrict__ v,
                                              unsigned short* __restrict__ rbf0) {
    const size_t i = (size_t)blockIdx.x * 256 + threadIdx.x;
#pragma unroll
    for (int k = 0; k < 4; ++k) {
        const size_t idx = i + (size_t)k * 262144;
        const float val = r0[idx];
        r[idx] = val; m[idx] = 0.f; v[idx] = 0.f; rbf0[idx] = f2bf(val);
    }
}

// ---- 64x64-tile bf16 MFMA GEMM: C[m][n] = sum_k A[m][k] * Bt[n][k].
// EPI 0: store bf16 (G). EPI 1: store f32 (u). EPI 2: fused Adam step + loss.
template <int EPI>
__global__ __launch_bounds__(256) void gemm64(
        const unsigned short* __restrict__ A, int lda,
        const unsigned short* __restrict__ Bt, int ldb, int K,
        unsigned short* __restrict__ Cb, float* __restrict__ Cf, int ldc,
        float* __restrict__ rbuf, float* __restrict__ mbuf, float* __restrict__ vbuf,
        const float* __restrict__ ubuf, const float* __restrict__ bvec,
        unsigned short* __restrict__ rbf_out, float* __restrict__ lossRow,
        float inv1, float inv2) {
    __shared__ alignas(16) unsigned short Al[2][64 * 64];
    __shared__ alignas(16) unsigned short Bl[2][64 * 64];
    const int t = threadIdx.x, w = t >> 6, lane = t & 63;
    const int wm = w >> 1, wn = w & 1;
    const int m0 = blockIdx.y * 64, n0 = blockIdx.x * 64;

    f32x4 acc[2][2] = {};

    // Stage 64x64 bf16 tile (8 KB) via global_load_lds width-16.
    // LDS dest is linear (lane*16); the XOR swizzle (16B-group g ^= row&7) is
    // applied to the *global source* (Guideline 21) and undone on the read side.
    auto stage = [&](int buf, int k0) {
#pragma unroll
        for (int h = 0; h < 2; ++h) {
            const int c = h * 256 + t;
            const int row = c >> 3, g = c & 7;
            const int gl = g ^ (row & 7);
            const unsigned short* ga = A + (size_t)(m0 + row) * lda + k0 + gl * 8;
            const unsigned short* gb = Bt + (size_t)(n0 + row) * ldb + k0 + gl * 8;
            unsigned short* la = &Al[buf][(h * 256 + w * 64) * 8];
            unsigned short* lb = &Bl[buf][(h * 256 + w * 64) * 8];
            __builtin_amdgcn_global_load_lds((const __attribute__((address_space(1))) void*)ga,
                                             (__attribute__((address_space(3))) void*)la, 16, 0, 0);
            __builtin_amdgcn_global_load_lds((const __attribute__((address_space(1))) void*)gb,
                                             (__attribute__((address_space(3))) void*)lb, 16, 0, 0);
        }
    };

    stage(0, 0);
    const int nK = K >> 6;  // BK = 64
    for (int kt = 0; kt < nK; ++kt) {
        __syncthreads();  // drains vmcnt(0): staged tile ready; also guards buffer reuse
        const int cur = kt & 1;
        if (kt + 1 < nK) stage(cur ^ 1, (kt + 1) << 6);
        const unsigned short* a_base = Al[cur];
        const unsigned short* b_base = Bl[cur];
#pragma unroll
        for (int kh = 0; kh < 2; ++kh) {
            short8 av[2], bv[2];
#pragma unroll
            for (int i = 0; i < 2; ++i) {
                const int row = wm * 32 + i * 16 + (lane & 15);
                const int g = (kh * 4 + (lane >> 4)) ^ (row & 7);
                av[i] = *(const short8*)(a_base + row * 64 + g * 8);
            }
#pragma unroll
            for (int j = 0; j < 2; ++j) {
                const int row = wn * 32 + j * 16 + (lane & 15);
                const int g = (kh * 4 + (lane >> 4)) ^ (row & 7);
                bv[j] = *(const short8*)(b_base + row * 64 + g * 8);
            }
#pragma unroll
            for (int i = 0; i < 2; ++i)
#pragma unroll
                for (int j = 0; j < 2; ++j)
                    acc[i][j] = __builtin_amdgcn_mfma_f32_16x16x32_bf16(av[i], bv[j], acc[i][j], 0, 0, 0);
        }
    }

    float lpart = 0.f;
#pragma unroll
    for (int i = 0; i < 2; ++i) {
#pragma unroll
        for (int j = 0; j < 2; ++j) {
            const int col = n0 + wn * 32 + j * 16 + (lane & 15);
            const int row0 = m0 + wm * 32 + i * 16 + ((lane >> 4) << 2);  // C/D: col=lane&15, row=(lane>>4)*4+q
#pragma unroll
            for (int q = 0; q < 4; ++q) {
                const int rowg = row0 + q;
                const float s = acc[i][j][q];
                if constexpr (EPI == 0) {
                    Cb[(size_t)rowg * ldc + col] = f2bf(s);
                } else if constexpr (EPI == 1) {
                    Cf[(size_t)rowg * ldc + col] = s;
                } else {
                    const size_t idx = (size_t)rowg * ldc + col;
                    const float rold = rbuf[idx];
                    const float be = bvec[col];
                    const float ue = ubuf[idx];
                    const float g = (2.0f / B_SZ) * (rold - be - ue + s);
                    lpart += (rold - be) * (rold - be) + rold * (s - 2.0f * ue);
                    const float m1 = 0.9f * mbuf[idx] + 0.1f * g;
                    const float v1 = 0.999f * vbuf[idx] + 0.001f * (g * g);
                    mbuf[idx] = m1;
                    vbuf[idx] = v1;
                    const float rn = rold - 0.01f * (m1 * inv1) / (sqrtf(v1 * inv2) + 1e-8f);
                    rbuf[idx] = rn;
                    rbf_out[idx] = f2bf(rn);
                }
            }
        }
    }
    if constexpr (EPI == 2) {
#pragma unroll
        for (int off = 32; off > 0; off >>= 1) lpart += __shfl_down(lpart, off);
        __shared__ float wred[4];
        if (lane == 0) wred[w] = lpart;
        __syncthreads();
        if (t == 0) lossRow[blockIdx.y * gridDim.x + blockIdx.x] = wred[0] + wred[1] + wred[2] + wred[3];
    }
}

// ---- losses[t] = (sum_blocks lossPart + sum_b xc2) / B ----
__global__ __launch_bounds__(256) void k_finalize(const float* __restrict__ lossPart,
                                                  const float* __restrict__ xc2, float* __restrict__ out) {
    const int it = blockIdx.x, t = threadIdx.x;
    float p = lossPart[it * 256 + t] + xc2[t] + xc2[t + 256];
#pragma unroll
    for (int off = 32; off > 0; off >>= 1) p += __shfl_down(p, off);
    __shared__ float wred[4];
    if ((t & 63) == 0) wred[t >> 6] = p;
    __syncthreads();
    if (t == 0) out[(size_t)B_SZ * H_SZ + it] = (wred[0] + wred[1] + wred[2] + wred[3]) * (1.0f / B_SZ);
}

__global__ __launch_bounds__(256) void k_copy(const float* __restrict__ r, float* __restrict__ out) {
    const size_t i = ((size_t)blockIdx.x * 256 + threadIdx.x) * 4;
    *(float4*)(out + i) = *(const float4*)(r + i);
}

extern "C" void kernel_launch(void* const* d_in, const int* in_sizes, int n_in,
                              void* d_out, int out_size, void* d_ws, size_t ws_size,
                              hipStream_t stream) {
    const float* x = (const float*)d_in[0];
    const float* W = (const float*)d_in[1];
    const float* cvec = (const float*)d_in[2];
    const float* bvec = (const float*)d_in[3];
    const float* r0 = (const float*)d_in[4];
    float* out = (float*)d_out;
    char* ws = (char*)d_ws;

    unsigned short* Wt = (unsigned short*)(ws);              // 16 MB   (H x D bf16)
    unsigned short* Gbf = (unsigned short*)(ws + 16777216);  // 8 MB    (H x H bf16)
    unsigned short* xcbf = (unsigned short*)(ws + 25165824); // 4 MB    (B x D bf16)
    float* u = (float*)(ws + 29360128);                      // 4 MB    (B x H f32)
    float* r = (float*)(ws + 33554432);                      // 4 MB
    float* m = (float*)(ws + 37748736);                      // 4 MB
    float* v = (float*)(ws + 41943040);                      // 4 MB
    unsigned short* rbf0 = (unsigned short*)(ws + 46137344); // 2 MB
    unsigned short* rbf1 = (unsigned short*)(ws + 48234496); // 2 MB
    float* xc2 = (float*)(ws + 50331648);                    // 2 KB
    float* lossPart = (float*)(ws + 50333696);               // 100 KB  (ITERS x 256)

    k_transpose<<<dim3(64, 32), 256, 0, stream>>>(W, Wt);
    k_prepx<<<512, 256, 0, stream>>>(x, cvec, xcbf, xc2);
    k_init<<<1024, 256, 0, stream>>>(r0, r, m, v, rbf0);
    // G = Wt @ Wt^T (i.e. W^T W), M=N=2048, K=4096
    gemm64<0><<<dim3(32, 32), 256, 0, stream>>>(Wt, D_SZ, Wt, D_SZ, D_SZ, Gbf, nullptr, H_SZ,
                                                nullptr, nullptr, nullptr, nullptr, nullptr,
                                                nullptr, nullptr, 0.f, 0.f);
    // u = (x-c) @ W, M=512, N=2048, K=4096
    gemm64<1><<<dim3(32, 8), 256, 0, stream>>>(xcbf, D_SZ, Wt, D_SZ, D_SZ, nullptr, u, H_SZ,
                                               nullptr, nullptr, nullptr, nullptr, nullptr,
                                               nullptr, nullptr, 0.f, 0.f);
    for (int it = 0; it < ITERS; ++it) {
        const float inv1 = (float)(1.0 / (1.0 - std::pow(0.9, (double)(it + 1))));
        const float inv2 = (float)(1.0 / (1.0 - std::pow(0.999, (double)(it + 1))));
        const unsigned short* rin = (it & 1) ? rbf1 : rbf0;
        unsigned short* rout = (it & 1) ? rbf0 : rbf1;
        gemm64<2><<<dim3(32, 8), 256, 0, stream>>>(rin, H_SZ, Gbf, H_SZ, H_SZ, nullptr, nullptr, H_SZ,
                                                   r, m, v, u, bvec, rout, lossPart + (size_t)it * 256,
                                                   inv1, inv2);
    }
    k_finalize<<<ITERS, 256, 0, stream>>>(lossPart, xc2, out);
    k_copy<<<1024, 256, 0, stream>>>(r, out);
}

// Round 3
// 2478.535 us; speedup vs baseline: 1.1636x; 1.1636x over previous
//
#include <hip/hip_runtime.h>
#include <cmath>

// Memory_76957224010242: 100-step Adam inference loop.
// G = W^T W, u = (x-c)@W once; per-iter s = r@G fused with Adam + loss.
// R3 change: loop GEMM tile 64x64 -> 32x64 (grid 256 -> 512 = 2 blocks/CU) to fix
// the occupancy-bound 159 TF (vs 662 TF for the same code at 4 blocks/CU).

#define B_SZ 512
#define H_SZ 2048
#define D_SZ 4096
#define ITERS 100

typedef __attribute__((ext_vector_type(8))) short short8;
typedef __attribute__((ext_vector_type(4))) float f32x4;

__device__ __forceinline__ unsigned short f2bf(float f) {
    unsigned u = __float_as_uint(f);
    u = (u + 0x7fffu + ((u >> 16) & 1u)) >> 16;  // RNE
    return (unsigned short)u;
}

__device__ __forceinline__ void gload_lds16(const unsigned short* g, unsigned short* l) {
    __builtin_amdgcn_global_load_lds((const __attribute__((address_space(1))) void*)g,
                                     (__attribute__((address_space(3))) void*)l, 16, 0, 0);
}

// ---- W (D,H) f32 -> Wt (H,D) bf16 (transpose + cast) ----
__global__ __launch_bounds__(256) void k_transpose(const float* __restrict__ W,
                                                   unsigned short* __restrict__ Wt) {
    __shared__ unsigned short tile[64][72];
    const int d0 = blockIdx.x * 64, h0 = blockIdx.y * 64;
    const int t = threadIdx.x;
    const int lr = t >> 6, lc = t & 63;
#pragma unroll
    for (int rr = 0; rr < 16; ++rr) {
        const int dl = rr * 4 + lr;
        tile[dl][lc] = f2bf(W[(size_t)(d0 + dl) * H_SZ + h0 + lc]);
    }
    __syncthreads();
#pragma unroll
    for (int rr = 0; rr < 16; ++rr) {
        const int hl = rr * 4 + lr;
        Wt[(size_t)(h0 + hl) * D_SZ + d0 + lc] = tile[lc][hl];
    }
}

// ---- xc = (x - c) bf16, xc2[b] = sum_d (x-c)^2 ----
__global__ __launch_bounds__(256) void k_prepx(const float* __restrict__ x, const float* __restrict__ c,
                                               unsigned short* __restrict__ xcbf, float* __restrict__ xc2) {
    const int b = blockIdx.x, t = threadIdx.x;
    const float* xr = x + (size_t)b * D_SZ;
    unsigned short* orow = xcbf + (size_t)b * D_SZ;
    float acc = 0.f;
#pragma unroll
    for (int ch = 0; ch < 2; ++ch) {
        const int base = (ch * 256 + t) * 8;
        const float4 v0 = *(const float4*)(xr + base);
        const float4 v1 = *(const float4*)(xr + base + 4);
        const float4 c0 = *(const float4*)(c + base);
        const float4 c1 = *(const float4*)(c + base + 4);
        const float e0 = v0.x - c0.x, e1 = v0.y - c0.y, e2 = v0.z - c0.z, e3 = v0.w - c0.w;
        const float e4 = v1.x - c1.x, e5 = v1.y - c1.y, e6 = v1.z - c1.z, e7 = v1.w - c1.w;
        acc += e0 * e0 + e1 * e1 + e2 * e2 + e3 * e3 + e4 * e4 + e5 * e5 + e6 * e6 + e7 * e7;
        short8 ov;
        ov[0] = (short)f2bf(e0); ov[1] = (short)f2bf(e1); ov[2] = (short)f2bf(e2); ov[3] = (short)f2bf(e3);
        ov[4] = (short)f2bf(e4); ov[5] = (short)f2bf(e5); ov[6] = (short)f2bf(e6); ov[7] = (short)f2bf(e7);
        *(short8*)(orow + base) = ov;
    }
#pragma unroll
    for (int off = 32; off > 0; off >>= 1) acc += __shfl_down(acc, off);
    __shared__ float wred[4];
    if ((t & 63) == 0) wred[t >> 6] = acc;
    __syncthreads();
    if (t == 0) xc2[b] = wred[0] + wred[1] + wred[2] + wred[3];
}

// ---- r = r0; m = v = 0; rbf0 = bf16(r0) ----
__global__ __launch_bounds__(256) void k_init(const float* __restrict__ r0, float* __restrict__ r,
                                              float* __restrict__ m, float* __restrict__ v,
                                              unsigned short* __restrict__ rbf0) {
    const size_t i = (size_t)blockIdx.x * 256 + threadIdx.x;
#pragma unroll
    for (int k = 0; k < 4; ++k) {
        const size_t idx = i + (size_t)k * 262144;
        const float val = r0[idx];
        r[idx] = val; m[idx] = 0.f; v[idx] = 0.f; rbf0[idx] = f2bf(val);
    }
}

// ---- TM x 64 tile bf16 MFMA GEMM: C[m][n] = sum_k A[m][k] * Bt[n][k].
// TM=64: 4 waves as 2x2, each 32x32.  TM=32: 4 waves as 1x4, each 32rows x 16cols.
// EPI 0: store bf16 (G). EPI 1: store f32 (u). EPI 2: fused Adam step + loss.
template <int TM, int EPI>
__global__ __launch_bounds__(256) void gemm64(
        const unsigned short* __restrict__ A, int lda,
        const unsigned short* __restrict__ Bt, int ldb, int K,
        unsigned short* __restrict__ Cb, float* __restrict__ Cf, int ldc,
        float* __restrict__ rbuf, float* __restrict__ mbuf, float* __restrict__ vbuf,
        const float* __restrict__ ubuf, const float* __restrict__ bvec,
        unsigned short* __restrict__ rbf_out, float* __restrict__ lossRow,
        float inv1, float inv2) {
    __shared__ alignas(16) unsigned short Al[2][TM * 64];
    __shared__ alignas(16) unsigned short Bl[2][64 * 64];
    const int t = threadIdx.x, w = t >> 6, lane = t & 63;
    const int m0 = blockIdx.y * TM, n0 = blockIdx.x * 64;
    constexpr int NJ = (TM == 64) ? 2 : 1;
    const int row_base = (TM == 64) ? (w >> 1) * 32 : 0;        // wave's A-row offset
    const int col_base = (TM == 64) ? (w & 1) * 32 : w * 16;    // wave's B-row (col) offset

    f32x4 acc[2][NJ] = {};

    // LDS dest linear (wave-uniform base + lane*16B); XOR swizzle (g ^= row&7)
    // applied to the global source and undone on the read side (Guideline 21).
    auto stage = [&](int buf, int k0) {
#pragma unroll
        for (int h = 0; h < 2; ++h) {
            const int c = h * 256 + t;
            const int row = c >> 3, g = c & 7;
            const int gl = g ^ (row & 7);
            gload_lds16(Bt + (size_t)(n0 + row) * ldb + k0 + gl * 8, &Bl[buf][(h * 256 + w * 64) * 8]);
        }
        if constexpr (TM == 64) {
#pragma unroll
            for (int h = 0; h < 2; ++h) {
                const int c = h * 256 + t;
                const int row = c >> 3, g = c & 7;
                const int gl = g ^ (row & 7);
                gload_lds16(A + (size_t)(m0 + row) * lda + k0 + gl * 8, &Al[buf][(h * 256 + w * 64) * 8]);
            }
        } else {
            const int row = t >> 3, g = t & 7;
            const int gl = g ^ (row & 7);
            gload_lds16(A + (size_t)(m0 + row) * lda + k0 + gl * 8, &Al[buf][(w * 64) * 8]);
        }
    };

    stage(0, 0);
    const int nK = K >> 6;  // BK = 64
    for (int kt = 0; kt < nK; ++kt) {
        __syncthreads();  // drains vmcnt(0): staged tile ready; also guards buffer reuse
        const int cur = kt & 1;
        if (kt + 1 < nK) stage(cur ^ 1, (kt + 1) << 6);
        const unsigned short* a_base = Al[cur];
        const unsigned short* b_base = Bl[cur];
#pragma unroll
        for (int kh = 0; kh < 2; ++kh) {
            short8 av[2], bv[NJ];
#pragma unroll
            for (int i = 0; i < 2; ++i) {
                const int row = row_base + i * 16 + (lane & 15);
                const int g = (kh * 4 + (lane >> 4)) ^ (row & 7);
                av[i] = *(const short8*)(a_base + row * 64 + g * 8);
            }
#pragma unroll
            for (int j = 0; j < NJ; ++j) {
                const int row = col_base + j * 16 + (lane & 15);
                const int g = (kh * 4 + (lane >> 4)) ^ (row & 7);
                bv[j] = *(const short8*)(b_base + row * 64 + g * 8);
            }
#pragma unroll
            for (int i = 0; i < 2; ++i)
#pragma unroll
                for (int j = 0; j < NJ; ++j)
                    acc[i][j] = __builtin_amdgcn_mfma_f32_16x16x32_bf16(av[i], bv[j], acc[i][j], 0, 0, 0);
        }
    }

    float lpart = 0.f;
#pragma unroll
    for (int i = 0; i < 2; ++i) {
#pragma unroll
        for (int j = 0; j < NJ; ++j) {
            const int col = n0 + col_base + j * 16 + (lane & 15);
            const int row0 = m0 + row_base + i * 16 + ((lane >> 4) << 2);  // C/D: col=lane&15, row=(lane>>4)*4+q
#pragma unroll
            for (int q = 0; q < 4; ++q) {
                const int rowg = row0 + q;
                const float s = acc[i][j][q];
                if constexpr (EPI == 0) {
                    Cb[(size_t)rowg * ldc + col] = f2bf(s);
                } else if constexpr (EPI == 1) {
                    Cf[(size_t)rowg * ldc + col] = s;
                } else {
                    const size_t idx = (size_t)rowg * ldc + col;
                    const float rold = rbuf[idx];
                    const float be = bvec[col];
                    const float ue = ubuf[idx];
                    const float g = (2.0f / B_SZ) * (rold - be - ue + s);
                    lpart += (rold - be) * (rold - be) + rold * (s - 2.0f * ue);
                    const float m1 = 0.9f * mbuf[idx] + 0.1f * g;
                    const float v1 = 0.999f * vbuf[idx] + 0.001f * (g * g);
                    mbuf[idx] = m1;
                    vbuf[idx] = v1;
                    const float rn = rold - 0.01f * (m1 * inv1) / (sqrtf(v1 * inv2) + 1e-8f);
                    rbuf[idx] = rn;
                    rbf_out[idx] = f2bf(rn);
                }
            }
        }
    }
    if constexpr (EPI == 2) {
#pragma unroll
        for (int off = 32; off > 0; off >>= 1) lpart += __shfl_down(lpart, off);
        __shared__ float wred[4];
        if (lane == 0) wred[w] = lpart;
        __syncthreads();
        if (t == 0) lossRow[blockIdx.y * gridDim.x + blockIdx.x] = wred[0] + wred[1] + wred[2] + wred[3];
    }
}

// ---- losses[t] = (sum_blocks lossPart + sum_b xc2) / B ----  (512 partials/iter)
__global__ __launch_bounds__(256) void k_finalize(const float* __restrict__ lossPart,
                                                  const float* __restrict__ xc2, float* __restrict__ out) {
    const int it = blockIdx.x, t = threadIdx.x;
    float p = lossPart[it * 512 + t] + lossPart[it * 512 + 256 + t] + xc2[t] + xc2[t + 256];
#pragma unroll
    for (int off = 32; off > 0; off >>= 1) p += __shfl_down(p, off);
    __shared__ float wred[4];
    if ((t & 63) == 0) wred[t >> 6] = p;
    __syncthreads();
    if (t == 0) out[(size_t)B_SZ * H_SZ + it] = (wred[0] + wred[1] + wred[2] + wred[3]) * (1.0f / B_SZ);
}

__global__ __launch_bounds__(256) void k_copy(const float* __restrict__ r, float* __restrict__ out) {
    const size_t i = ((size_t)blockIdx.x * 256 + threadIdx.x) * 4;
    *(float4*)(out + i) = *(const float4*)(r + i);
}

extern "C" void kernel_launch(void* const* d_in, const int* in_sizes, int n_in,
                              void* d_out, int out_size, void* d_ws, size_t ws_size,
                              hipStream_t stream) {
    const float* x = (const float*)d_in[0];
    const float* W = (const float*)d_in[1];
    const float* cvec = (const float*)d_in[2];
    const float* bvec = (const float*)d_in[3];
    const float* r0 = (const float*)d_in[4];
    float* out = (float*)d_out;
    char* ws = (char*)d_ws;

    unsigned short* Wt = (unsigned short*)(ws);              // 16 MB   (H x D bf16)
    unsigned short* Gbf = (unsigned short*)(ws + 16777216);  // 8 MB    (H x H bf16)
    unsigned short* xcbf = (unsigned short*)(ws + 25165824); // 4 MB    (B x D bf16)
    float* u = (float*)(ws + 29360128);                      // 4 MB    (B x H f32)
    float* r = (float*)(ws + 33554432);                      // 4 MB
    float* m = (float*)(ws + 37748736);                      // 4 MB
    float* v = (float*)(ws + 41943040);                      // 4 MB
    unsigned short* rbf0 = (unsigned short*)(ws + 46137344); // 2 MB
    unsigned short* rbf1 = (unsigned short*)(ws + 48234496); // 2 MB
    float* xc2 = (float*)(ws + 50331648);                    // 2 KB
    float* lossPart = (float*)(ws + 50333696);               // 200 KB  (ITERS x 512)

    k_transpose<<<dim3(64, 32), 256, 0, stream>>>(W, Wt);
    k_prepx<<<512, 256, 0, stream>>>(x, cvec, xcbf, xc2);
    k_init<<<1024, 256, 0, stream>>>(r0, r, m, v, rbf0);
    // G = Wt @ Wt^T (i.e. W^T W), M=N=2048, K=4096 (1024 blocks, 4/CU)
    gemm64<64, 0><<<dim3(32, 32), 256, 0, stream>>>(Wt, D_SZ, Wt, D_SZ, D_SZ, Gbf, nullptr, H_SZ,
                                                    nullptr, nullptr, nullptr, nullptr, nullptr,
                                                    nullptr, nullptr, 0.f, 0.f);
    // u = (x-c) @ W, M=512, N=2048, K=4096 (512 blocks, 2/CU)
    gemm64<32, 1><<<dim3(32, 16), 256, 0, stream>>>(xcbf, D_SZ, Wt, D_SZ, D_SZ, nullptr, u, H_SZ,
                                                    nullptr, nullptr, nullptr, nullptr, nullptr,
                                                    nullptr, nullptr, 0.f, 0.f);
    for (int it = 0; it < ITERS; ++it) {
        const float inv1 = (float)(1.0 / (1.0 - std::pow(0.9, (double)(it + 1))));
        const float inv2 = (float)(1.0 / (1.0 - std::pow(0.999, (double)(it + 1))));
        const unsigned short* rin = (it & 1) ? rbf1 : rbf0;
        unsigned short* rout = (it & 1) ? rbf0 : rbf1;
        gemm64<32, 2><<<dim3(32, 16), 256, 0, stream>>>(rin, H_SZ, Gbf, H_SZ, H_SZ, nullptr, nullptr, H_SZ,
                                                        r, m, v, u, bvec, rout, lossPart + (size_t)it * 512,
                                                        inv1, inv2);
    }
    k_finalize<<<ITERS, 256, 0, stream>>>(lossPart, xc2, out);
    k_copy<<<1024, 256, 0, stream>>>(r, out);
}

// Round 4
// 2239.657 us; speedup vs baseline: 1.2877x; 1.1067x over previous
//
#include <hip/hip_runtime.h>
#include <cmath>

// Memory_76957224010242: 100-step Adam inference loop.
// G = W^T W, u = (x-c)@W once; per-iter s = r@G fused with Adam + loss.
// R4: epilogue state (r, u, packed m|v) prefetched into registers BEFORE the
// K-loop (hidden under MFMA); m,v packed bf16x2 in one u32 buffer (halves
// Adam-state traffic).

#define B_SZ 512
#define H_SZ 2048
#define D_SZ 4096
#define ITERS 100

typedef __attribute__((ext_vector_type(8))) short short8;
typedef __attribute__((ext_vector_type(4))) float f32x4;

__device__ __forceinline__ unsigned short f2bf(float f) {
    unsigned u = __float_as_uint(f);
    u = (u + 0x7fffu + ((u >> 16) & 1u)) >> 16;  // RNE
    return (unsigned short)u;
}
__device__ __forceinline__ float bflo(unsigned mv) { return __uint_as_float(mv << 16); }
__device__ __forceinline__ float bfhi(unsigned mv) { return __uint_as_float(mv & 0xffff0000u); }

__device__ __forceinline__ void gload_lds16(const unsigned short* g, unsigned short* l) {
    __builtin_amdgcn_global_load_lds((const __attribute__((address_space(1))) void*)g,
                                     (__attribute__((address_space(3))) void*)l, 16, 0, 0);
}

// ---- W (D,H) f32 -> Wt (H,D) bf16 (transpose + cast) ----
__global__ __launch_bounds__(256) void k_transpose(const float* __restrict__ W,
                                                   unsigned short* __restrict__ Wt) {
    __shared__ unsigned short tile[64][72];
    const int d0 = blockIdx.x * 64, h0 = blockIdx.y * 64;
    const int t = threadIdx.x;
    const int lr = t >> 6, lc = t & 63;
#pragma unroll
    for (int rr = 0; rr < 16; ++rr) {
        const int dl = rr * 4 + lr;
        tile[dl][lc] = f2bf(W[(size_t)(d0 + dl) * H_SZ + h0 + lc]);
    }
    __syncthreads();
#pragma unroll
    for (int rr = 0; rr < 16; ++rr) {
        const int hl = rr * 4 + lr;
        Wt[(size_t)(h0 + hl) * D_SZ + d0 + lc] = tile[lc][hl];
    }
}

// ---- xc = (x - c) bf16, xc2[b] = sum_d (x-c)^2 ----
__global__ __launch_bounds__(256) void k_prepx(const float* __restrict__ x, const float* __restrict__ c,
                                               unsigned short* __restrict__ xcbf, float* __restrict__ xc2) {
    const int b = blockIdx.x, t = threadIdx.x;
    const float* xr = x + (size_t)b * D_SZ;
    unsigned short* orow = xcbf + (size_t)b * D_SZ;
    float acc = 0.f;
#pragma unroll
    for (int ch = 0; ch < 2; ++ch) {
        const int base = (ch * 256 + t) * 8;
        const float4 v0 = *(const float4*)(xr + base);
        const float4 v1 = *(const float4*)(xr + base + 4);
        const float4 c0 = *(const float4*)(c + base);
        const float4 c1 = *(const float4*)(c + base + 4);
        const float e0 = v0.x - c0.x, e1 = v0.y - c0.y, e2 = v0.z - c0.z, e3 = v0.w - c0.w;
        const float e4 = v1.x - c1.x, e5 = v1.y - c1.y, e6 = v1.z - c1.z, e7 = v1.w - c1.w;
        acc += e0 * e0 + e1 * e1 + e2 * e2 + e3 * e3 + e4 * e4 + e5 * e5 + e6 * e6 + e7 * e7;
        short8 ov;
        ov[0] = (short)f2bf(e0); ov[1] = (short)f2bf(e1); ov[2] = (short)f2bf(e2); ov[3] = (short)f2bf(e3);
        ov[4] = (short)f2bf(e4); ov[5] = (short)f2bf(e5); ov[6] = (short)f2bf(e6); ov[7] = (short)f2bf(e7);
        *(short8*)(orow + base) = ov;
    }
#pragma unroll
    for (int off = 32; off > 0; off >>= 1) acc += __shfl_down(acc, off);
    __shared__ float wred[4];
    if ((t & 63) == 0) wred[t >> 6] = acc;
    __syncthreads();
    if (t == 0) xc2[b] = wred[0] + wred[1] + wred[2] + wred[3];
}

// ---- r = r0; mv = 0; rbf0 = bf16(r0) ----
__global__ __launch_bounds__(256) void k_init(const float* __restrict__ r0, float* __restrict__ r,
                                              unsigned* __restrict__ mv,
                                              unsigned short* __restrict__ rbf0) {
    const size_t i = (size_t)blockIdx.x * 256 + threadIdx.x;
#pragma unroll
    for (int k = 0; k < 4; ++k) {
        const size_t idx = i + (size_t)k * 262144;
        const float val = r0[idx];
        r[idx] = val; mv[idx] = 0u; rbf0[idx] = f2bf(val);
    }
}

// ---- TM x 64 tile bf16 MFMA GEMM: C[m][n] = sum_k A[m][k] * Bt[n][k].
// TM=64: 4 waves as 2x2, each 32x32.  TM=32: 4 waves as 1x4, each 32rows x 16cols.
// EPI 0: store bf16 (G). EPI 1: store f32 (u). EPI 2: fused Adam step + loss.
template <int TM, int EPI>
__global__ __launch_bounds__(256) void gemm64(
        const unsigned short* __restrict__ A, int lda,
        const unsigned short* __restrict__ Bt, int ldb, int K,
        unsigned short* __restrict__ Cb, float* __restrict__ Cf, int ldc,
        float* __restrict__ rbuf, unsigned* __restrict__ mvbuf,
        const float* __restrict__ ubuf, const float* __restrict__ bvec,
        unsigned short* __restrict__ rbf_out, float* __restrict__ lossRow,
        float inv1, float inv2) {
    __shared__ alignas(16) unsigned short Al[2][TM * 64];
    __shared__ alignas(16) unsigned short Bl[2][64 * 64];
    const int t = threadIdx.x, w = t >> 6, lane = t & 63;
    const int m0 = blockIdx.y * TM, n0 = blockIdx.x * 64;
    constexpr int NJ = (TM == 64) ? 2 : 1;
    const int row_base = (TM == 64) ? (w >> 1) * 32 : 0;        // wave's A-row offset
    const int col_base = (TM == 64) ? (w & 1) * 32 : w * 16;    // wave's B-row (col) offset

    f32x4 acc[2][NJ] = {};

    // LDS dest linear (wave-uniform base + lane*16B); XOR swizzle (g ^= row&7)
    // applied to the global source and undone on the read side (Guideline 21).
    auto stage = [&](int buf, int k0) {
#pragma unroll
        for (int h = 0; h < 2; ++h) {
            const int c = h * 256 + t;
            const int row = c >> 3, g = c & 7;
            const int gl = g ^ (row & 7);
            gload_lds16(Bt + (size_t)(n0 + row) * ldb + k0 + gl * 8, &Bl[buf][(h * 256 + w * 64) * 8]);
        }
        if constexpr (TM == 64) {
#pragma unroll
            for (int h = 0; h < 2; ++h) {
                const int c = h * 256 + t;
                const int row = c >> 3, g = c & 7;
                const int gl = g ^ (row & 7);
                gload_lds16(A + (size_t)(m0 + row) * lda + k0 + gl * 8, &Al[buf][(h * 256 + w * 64) * 8]);
            }
        } else {
            const int row = t >> 3, g = t & 7;
            const int gl = g ^ (row & 7);
            gload_lds16(A + (size_t)(m0 + row) * lda + k0 + gl * 8, &Al[buf][(w * 64) * 8]);
        }
    };

    stage(0, 0);

    // Prefetch epilogue state into registers; these ~25 loads complete under
    // the 32 K-step MFMA loop (issued now, consumed after the loop).
    float pre_r[2 * NJ * 4], pre_u[2 * NJ * 4], pre_b[NJ];
    unsigned pre_mv[2 * NJ * 4];
    if constexpr (EPI == 2) {
#pragma unroll
        for (int i = 0; i < 2; ++i)
#pragma unroll
            for (int j = 0; j < NJ; ++j) {
                const int col = n0 + col_base + j * 16 + (lane & 15);
                const int row0 = m0 + row_base + i * 16 + ((lane >> 4) << 2);
                if (i == 0) pre_b[j] = bvec[col];
#pragma unroll
                for (int q = 0; q < 4; ++q) {
                    const size_t idx = (size_t)(row0 + q) * ldc + col;
                    const int e = (i * NJ + j) * 4 + q;
                    pre_r[e] = rbuf[idx];
                    pre_u[e] = ubuf[idx];
                    pre_mv[e] = mvbuf[idx];
                }
            }
    }

    const int nK = K >> 6;  // BK = 64
    for (int kt = 0; kt < nK; ++kt) {
        __syncthreads();  // drains vmcnt(0): staged tile ready; also guards buffer reuse
        const int cur = kt & 1;
        if (kt + 1 < nK) stage(cur ^ 1, (kt + 1) << 6);
        const unsigned short* a_base = Al[cur];
        const unsigned short* b_base = Bl[cur];
#pragma unroll
        for (int kh = 0; kh < 2; ++kh) {
            short8 av[2], bv[NJ];
#pragma unroll
            for (int i = 0; i < 2; ++i) {
                const int row = row_base + i * 16 + (lane & 15);
                const int g = (kh * 4 + (lane >> 4)) ^ (row & 7);
                av[i] = *(const short8*)(a_base + row * 64 + g * 8);
            }
#pragma unroll
            for (int j = 0; j < NJ; ++j) {
                const int row = col_base + j * 16 + (lane & 15);
                const int g = (kh * 4 + (lane >> 4)) ^ (row & 7);
                bv[j] = *(const short8*)(b_base + row * 64 + g * 8);
            }
#pragma unroll
            for (int i = 0; i < 2; ++i)
#pragma unroll
                for (int j = 0; j < NJ; ++j)
                    acc[i][j] = __builtin_amdgcn_mfma_f32_16x16x32_bf16(av[i], bv[j], acc[i][j], 0, 0, 0);
        }
    }

    float lpart = 0.f;
#pragma unroll
    for (int i = 0; i < 2; ++i) {
#pragma unroll
        for (int j = 0; j < NJ; ++j) {
            const int col = n0 + col_base + j * 16 + (lane & 15);
            const int row0 = m0 + row_base + i * 16 + ((lane >> 4) << 2);  // C/D: col=lane&15, row=(lane>>4)*4+q
#pragma unroll
            for (int q = 0; q < 4; ++q) {
                const int rowg = row0 + q;
                const float s = acc[i][j][q];
                if constexpr (EPI == 0) {
                    Cb[(size_t)rowg * ldc + col] = f2bf(s);
                } else if constexpr (EPI == 1) {
                    Cf[(size_t)rowg * ldc + col] = s;
                } else {
                    const size_t idx = (size_t)rowg * ldc + col;
                    const int e = (i * NJ + j) * 4 + q;
                    const float rold = pre_r[e];
                    const float ue = pre_u[e];
                    const float g = (2.0f / B_SZ) * (rold - pre_b[j] - ue + s);
                    lpart += (rold - pre_b[j]) * (rold - pre_b[j]) + rold * (s - 2.0f * ue);
                    const float m1 = 0.9f * bflo(pre_mv[e]) + 0.1f * g;
                    const float v1 = 0.999f * bfhi(pre_mv[e]) + 0.001f * (g * g);
                    mvbuf[idx] = (unsigned)f2bf(m1) | ((unsigned)f2bf(v1) << 16);
                    const float rn = rold - 0.01f * (m1 * inv1) / (sqrtf(v1 * inv2) + 1e-8f);
                    rbuf[idx] = rn;
                    rbf_out[idx] = f2bf(rn);
                }
            }
        }
    }
    if constexpr (EPI == 2) {
#pragma unroll
        for (int off = 32; off > 0; off >>= 1) lpart += __shfl_down(lpart, off);
        __shared__ float wred[4];
        if (lane == 0) wred[w] = lpart;
        __syncthreads();
        if (t == 0) lossRow[blockIdx.y * gridDim.x + blockIdx.x] = wred[0] + wred[1] + wred[2] + wred[3];
    }
}

// ---- losses[t] = (sum_blocks lossPart + sum_b xc2) / B ----  (512 partials/iter)
__global__ __launch_bounds__(256) void k_finalize(const float* __restrict__ lossPart,
                                                  const float* __restrict__ xc2, float* __restrict__ out) {
    const int it = blockIdx.x, t = threadIdx.x;
    float p = lossPart[it * 512 + t] + lossPart[it * 512 + 256 + t] + xc2[t] + xc2[t + 256];
#pragma unroll
    for (int off = 32; off > 0; off >>= 1) p += __shfl_down(p, off);
    __shared__ float wred[4];
    if ((t & 63) == 0) wred[t >> 6] = p;
    __syncthreads();
    if (t == 0) out[(size_t)B_SZ * H_SZ + it] = (wred[0] + wred[1] + wred[2] + wred[3]) * (1.0f / B_SZ);
}

__global__ __launch_bounds__(256) void k_copy(const float* __restrict__ r, float* __restrict__ out) {
    const size_t i = ((size_t)blockIdx.x * 256 + threadIdx.x) * 4;
    *(float4*)(out + i) = *(const float4*)(r + i);
}

extern "C" void kernel_launch(void* const* d_in, const int* in_sizes, int n_in,
                              void* d_out, int out_size, void* d_ws, size_t ws_size,
                              hipStream_t stream) {
    const float* x = (const float*)d_in[0];
    const float* W = (const float*)d_in[1];
    const float* cvec = (const float*)d_in[2];
    const float* bvec = (const float*)d_in[3];
    const float* r0 = (const float*)d_in[4];
    float* out = (float*)d_out;
    char* ws = (char*)d_ws;

    unsigned short* Wt = (unsigned short*)(ws);              // 16 MB   (H x D bf16)
    unsigned short* Gbf = (unsigned short*)(ws + 16777216);  // 8 MB    (H x H bf16)
    unsigned short* xcbf = (unsigned short*)(ws + 25165824); // 4 MB    (B x D bf16)
    float* u = (float*)(ws + 29360128);                      // 4 MB    (B x H f32)
    float* r = (float*)(ws + 33554432);                      // 4 MB
    unsigned* mv = (unsigned*)(ws + 37748736);               // 4 MB    (bf16 m | bf16 v packed)
    unsigned short* rbf0 = (unsigned short*)(ws + 41943040); // 2 MB
    unsigned short* rbf1 = (unsigned short*)(ws + 44040192); // 2 MB
    float* xc2 = (float*)(ws + 46137344);                    // 2 KB
    float* lossPart = (float*)(ws + 46139392);               // 200 KB  (ITERS x 512)

    k_transpose<<<dim3(64, 32), 256, 0, stream>>>(W, Wt);
    k_prepx<<<512, 256, 0, stream>>>(x, cvec, xcbf, xc2);
    k_init<<<1024, 256, 0, stream>>>(r0, r, mv, rbf0);
    // G = Wt @ Wt^T (i.e. W^T W), M=N=2048, K=4096 (1024 blocks, 4/CU)
    gemm64<64, 0><<<dim3(32, 32), 256, 0, stream>>>(Wt, D_SZ, Wt, D_SZ, D_SZ, Gbf, nullptr, H_SZ,
                                                    nullptr, nullptr, nullptr, nullptr,
                                                    nullptr, nullptr, 0.f, 0.f);
    // u = (x-c) @ W, M=512, N=2048, K=4096 (512 blocks, 2/CU)
    gemm64<32, 1><<<dim3(32, 16), 256, 0, stream>>>(xcbf, D_SZ, Wt, D_SZ, D_SZ, nullptr, u, H_SZ,
                                                    nullptr, nullptr, nullptr, nullptr,
                                                    nullptr, nullptr, 0.f, 0.f);
    for (int it = 0; it < ITERS; ++it) {
        const float inv1 = (float)(1.0 / (1.0 - std::pow(0.9, (double)(it + 1))));
        const float inv2 = (float)(1.0 / (1.0 - std::pow(0.999, (double)(it + 1))));
        const unsigned short* rin = (it & 1) ? rbf1 : rbf0;
        unsigned short* rout = (it & 1) ? rbf0 : rbf1;
        gemm64<32, 2><<<dim3(32, 16), 256, 0, stream>>>(rin, H_SZ, Gbf, H_SZ, H_SZ, nullptr, nullptr, H_SZ,
                                                        r, mv, u, bvec, rout, lossPart + (size_t)it * 512,
                                                        inv1, inv2);
    }
    k_finalize<<<ITERS, 256, 0, stream>>>(lossPart, xc2, out);
    k_copy<<<1024, 256, 0, stream>>>(r, out);
}